// Round 2
// baseline (935.031 us; speedup 1.0000x reference)
//
#include <hip/hip_runtime.h>
#include <cstdint>
#include <cstddef>

#define LQ 1024
#define LK 4096
#define NBATCH 8
#define DM 256
#define NH 4

typedef __attribute__((ext_vector_type(8))) __bf16 bf16x8;
typedef __attribute__((ext_vector_type(4))) float f32x4;
typedef __attribute__((ext_vector_type(16))) float f32x16;
typedef __attribute__((ext_vector_type(4))) unsigned int u32x4;
typedef __attribute__((ext_vector_type(4))) short s16x4;

__device__ __forceinline__ unsigned short f2bf(float f) {
  unsigned int u = __builtin_bit_cast(unsigned int, f);
  u += 0x7FFFu + ((u >> 16) & 1u);  // RNE
  return (unsigned short)(u >> 16);
}
__device__ __forceinline__ unsigned pack2(float a, float b) {
  return (unsigned)f2bf(a) | ((unsigned)f2bf(b) << 16);
}
__device__ __forceinline__ bf16x8 ld_bf8(const unsigned short* p) {
  u32x4 u = *reinterpret_cast<const u32x4*>(p);
  return __builtin_bit_cast(bf16x8, u);
}
__device__ __forceinline__ f32x4 zero4() {
  f32x4 v; v.x = 0.f; v.y = 0.f; v.z = 0.f; v.w = 0.f; return v;
}

// async global->LDS, 16B per lane; LDS dest = wave-uniform base + lane*16
#define ASYNC16(ldsp, gp)                                                      \
  __builtin_amdgcn_global_load_lds(                                            \
      (const __attribute__((address_space(1))) unsigned int*)(gp),             \
      (__attribute__((address_space(3))) unsigned int*)(ldsp), 16, 0, 0)

// ---------------------------------------------------------------------------
// prep (x8 vectorized): out[(b*L+l)*256+d] = bf16(a[(l*8+b)*256+d] (+badd))
// ---------------------------------------------------------------------------
__global__ void prep_add_kernel(const float* __restrict__ a,
                                const float* __restrict__ badd,
                                unsigned short* __restrict__ out,
                                int L, int n8) {
  int i = blockIdx.x * blockDim.x + threadIdx.x;
  if (i >= n8) return;
  int base = i * 8;
  int d = base & 255;
  int rest = base >> 8;
  int bb = rest & 7, l = rest >> 3;
  f32x4 x0 = *reinterpret_cast<const f32x4*>(a + base);
  f32x4 x1 = *reinterpret_cast<const f32x4*>(a + base + 4);
  if (badd) {
    f32x4 y0 = *reinterpret_cast<const f32x4*>(badd + base);
    f32x4 y1 = *reinterpret_cast<const f32x4*>(badd + base + 4);
    x0 += y0; x1 += y1;
  }
  u32x4 o;
  o.x = pack2(x0.x, x0.y); o.y = pack2(x0.z, x0.w);
  o.z = pack2(x1.x, x1.y); o.w = pack2(x1.z, x1.w);
  *reinterpret_cast<u32x4*>(out + (((size_t)bb * L + l) << 8) + d) = o;
}

__global__ void conv_bf16_kernel(const float* __restrict__ src,
                                 unsigned short* __restrict__ dst, int n8) {
  int i = blockIdx.x * blockDim.x + threadIdx.x;
  if (i >= n8) return;
  int base = i * 8;
  f32x4 x0 = *reinterpret_cast<const f32x4*>(src + base);
  f32x4 x1 = *reinterpret_cast<const f32x4*>(src + base + 4);
  u32x4 o;
  o.x = pack2(x0.x, x0.y); o.y = pack2(x0.z, x0.w);
  o.z = pack2(x1.x, x1.y); o.w = pack2(x1.z, x1.w);
  *reinterpret_cast<u32x4*>(dst + base) = o;
}

// ---------------------------------------------------------------------------
// NT GEMM, m97-style: global_load_lds(16B) staging, XOR-swizzled chunks.
// C[m,n] = alpha * sum_k A[m,k]*B[n,k].  Tile 128x128x(BK=64), 256 threads.
// LDS tiles unpadded [128][64] shorts; logical 8-short chunk c at physical
// chunk c ^ (row&7)  -> conflict-free b128 reads.
// OUT_MODE 0: fp32 row-major; 1: bf16 row-major; 2: bf16 transposed+batchfold
// ---------------------------------------------------------------------------
template <int OUT_MODE>
__global__ void __launch_bounds__(256)
gemm_nt_kernel(const unsigned short* __restrict__ A, int lda, long long sA,
               const unsigned short* __restrict__ B, int ldb, long long sB,
               void* __restrict__ Cv, int ldc, long long sC,
               int K, float alpha) {
  __shared__ __align__(16) unsigned short As[128 * 64];
  __shared__ __align__(16) unsigned short Bs[128 * 64];
  const int t = threadIdx.x;
  const int bm0 = blockIdx.y * 128;
  const int bn0 = blockIdx.x * 128;
  A += (size_t)blockIdx.z * sA + (size_t)bm0 * lda;
  B += (size_t)blockIdx.z * sB + (size_t)bn0 * ldb;
  const int lane = t & 63, w = t >> 6;
  const int wm = (w >> 1) * 64, wn = (w & 1) * 64;
  const int lr = lane & 15, quad = lane >> 4;
  // staging: wave w call i covers rows w*32+i*8 + (lane>>3), phys chunk lane&7
  const int srl = lane >> 3;                  // row-within-8
  const int sc = (lane & 7) ^ (srl & 7);      // logical source chunk

  f32x4 acc[4][4];
#pragma unroll
  for (int i = 0; i < 4; ++i)
#pragma unroll
    for (int j = 0; j < 4; ++j) acc[i][j] = zero4();

  for (int k0 = 0; k0 < K; k0 += 64) {
#pragma unroll
    for (int i = 0; i < 4; ++i) {
      int r0 = w * 32 + i * 8;
      ASYNC16(&As[r0 * 64], &A[(size_t)(r0 + srl) * lda + k0 + sc * 8]);
      ASYNC16(&Bs[r0 * 64], &B[(size_t)(r0 + srl) * ldb + k0 + sc * 8]);
    }
    __syncthreads();
#pragma unroll
    for (int ks = 0; ks < 2; ++ks) {
      bf16x8 af[4], bfv[4];
#pragma unroll
      for (int i = 0; i < 4; ++i) {
        int m = wm + i * 16 + lr;
        int pc = (ks * 4 + quad) ^ (lr & 7);
        af[i] = ld_bf8(&As[m * 64 + pc * 8]);
      }
#pragma unroll
      for (int j = 0; j < 4; ++j) {
        int n = wn + j * 16 + lr;
        int pc = (ks * 4 + quad) ^ (lr & 7);
        bfv[j] = ld_bf8(&Bs[n * 64 + pc * 8]);
      }
#pragma unroll
      for (int i = 0; i < 4; ++i)
#pragma unroll
        for (int j = 0; j < 4; ++j)
          acc[i][j] = __builtin_amdgcn_mfma_f32_16x16x32_bf16(af[i], bfv[j], acc[i][j], 0, 0, 0);
    }
    __syncthreads();
  }

  // Epilogue. C/D: col=lane&15, row=quad*4+reg (m89-verified)
  if (OUT_MODE == 0) {
    float* C = (float*)Cv + (size_t)blockIdx.z * sC;
#pragma unroll
    for (int i = 0; i < 4; ++i) {
      int m0 = bm0 + wm + i * 16 + quad * 4;
#pragma unroll
      for (int j = 0; j < 4; ++j) {
        int n = bn0 + wn + j * 16 + lr;
#pragma unroll
        for (int r = 0; r < 4; ++r)
          C[(size_t)(m0 + r) * ldc + n] = acc[i][j][r] * alpha;
      }
    }
  } else if (OUT_MODE == 1) {
    unsigned short* C = (unsigned short*)Cv + (size_t)blockIdx.z * sC;
#pragma unroll
    for (int i = 0; i < 4; ++i) {
      int m0 = bm0 + wm + i * 16 + quad * 4;
#pragma unroll
      for (int j = 0; j < 4; ++j) {
        int n = bn0 + wn + j * 16 + lr;
#pragma unroll
        for (int r = 0; r < 4; ++r)
          C[(size_t)(m0 + r) * ldc + n] = f2bf(acc[i][j][r] * alpha);
      }
    }
  } else {
    // m = b*4096 + kpos -> row b*1024+n, col kpos
    unsigned short* C = (unsigned short*)Cv;
#pragma unroll
    for (int i = 0; i < 4; ++i) {
      int m0 = bm0 + wm + i * 16 + quad * 4;
      int bb = m0 >> 12;
      int kp = m0 & 4095;
#pragma unroll
      for (int j = 0; j < 4; ++j) {
        int n = bn0 + wn + j * 16 + lr;
        s16x4 pk;
#pragma unroll
        for (int r = 0; r < 4; ++r) pk[r] = (short)f2bf(acc[i][j][r] * alpha);
        *reinterpret_cast<s16x4*>(&C[((size_t)(bb * 1024 + n)) * 4096 + kp]) = pk;
      }
    }
  }
}

// ---------------------------------------------------------------------------
// Flash attention, 32x32x16 MFMA, no-max softmax (logits ~ +-0.5), k-split 2.
// grid (16=qt*2+ks, H, B), 256 thr = 4 waves; wave owns 32 q rows.
// S^T = K*Q^T so C cols = q; P -> A-layout via shfl_xor(32); V from VT tile.
// Writes UNNORMALIZED O partial (bf16, [ks][p][e][q]) + l partial (fp32).
// ---------------------------------------------------------------------------
__global__ void __launch_bounds__(256, 2)
attn_kernel(const unsigned short* __restrict__ Qg,
            const unsigned short* __restrict__ Kg,
            const unsigned short* __restrict__ VTg,
            unsigned short* __restrict__ Opart,
            float* __restrict__ lpart) {
  __shared__ __align__(16) unsigned short Kt[32 * 256];  // [kpos][d] swizzled
  __shared__ __align__(16) unsigned short Vt[256 * 32];  // [e][kpos] swizzled
  const int t = threadIdx.x;
  const int qt = blockIdx.x >> 1, ks = blockIdx.x & 1;
  const int h = blockIdx.y, b = blockIdx.z;
  const int lane = t & 63, w = t >> 6;
  const int lo = lane & 31, hi = lane >> 5;

  // Q fragments (B-operand: n=q=lo, k = hi*8+j), all 256 d in 64 VGPRs
  const int q = qt * 128 + w * 32 + lo;
  const unsigned short* Qrow = Qg + ((size_t)(b * 1024 + q)) * 1024 + h * 256;
  bf16x8 qf[16];
#pragma unroll
  for (int s = 0; s < 16; ++s) qf[s] = ld_bf8(&Qrow[s * 16 + hi * 8]);

  f32x16 Oacc[8];
#pragma unroll
  for (int nt = 0; nt < 8; ++nt)
#pragma unroll
    for (int r = 0; r < 16; ++r) Oacc[nt][r] = 0.f;
  float lsum = 0.f;

  const unsigned short* Kb = Kg + ((size_t)(b * 4096 + ks * 2048)) * 1024 + h * 256;
  const unsigned short* Vb = VTg + ((size_t)(b * 1024 + h * 256)) * 4096 + ks * 2048;

  for (int kt = 0; kt < 2048; kt += 32) {
    // stage K (32x256) and VT (256x32), 4 async16 each per wave, XOR swizzle
#pragma unroll
    for (int i = 0; i < 4; ++i) {
      int krow = w * 8 + i * 2 + (lane >> 5);
      int kc = (lane & 31) ^ (krow & 7);
      ASYNC16(&Kt[(w * 8 + i * 2) * 256], &Kb[(size_t)(kt + krow) * 1024 + kc * 8]);
      int ve = (w * 4 + i) * 16 + (lane >> 2);
      int vc = (lane & 3) ^ (ve & 3);
      ASYNC16(&Vt[(w * 4 + i) * 16 * 32], &Vb[(size_t)ve * 4096 + kt + vc * 8]);
    }
    __syncthreads();

    // S^T[kpos][q] : A = K (m=kpos=lo, k=d), B = Q regs
    f32x16 S;
#pragma unroll
    for (int r = 0; r < 16; ++r) S[r] = 0.f;
#pragma unroll
    for (int s = 0; s < 16; ++s) {
      int pc = (s * 2 + hi) ^ (lane & 7);
      bf16x8 kf = ld_bf8(&Kt[lo * 256 + pc * 8]);
      S = __builtin_amdgcn_mfma_f32_32x32x16_bf16(kf, qf[s], S, 0, 0, 0);
    }

    float p[16];
#pragma unroll
    for (int r = 0; r < 16; ++r) { p[r] = __expf(S[r]); lsum += p[r]; }

    // PV: O[q][e] += P*V, two ksteps of 16 kpos
#pragma unroll
    for (int s2 = 0; s2 < 2; ++s2) {
      int rbk = (2 * s2 + hi) * 4;
      int rbs = (2 * s2 + (hi ^ 1)) * 4;
      unsigned keep01 = pack2(p[rbk + 0], p[rbk + 1]);
      unsigned keep23 = pack2(p[rbk + 2], p[rbk + 3]);
      unsigned send01 = pack2(p[rbs + 0], p[rbs + 1]);
      unsigned send23 = pack2(p[rbs + 2], p[rbs + 3]);
      unsigned recv01 = __shfl_xor(send01, 32, 64);
      unsigned recv23 = __shfl_xor(send23, 32, 64);
      u32x4 aw;
      aw.x = hi ? recv01 : keep01;   // j0..1 (from hi_p=0 producer)
      aw.y = hi ? recv23 : keep23;   // j2..3
      aw.z = hi ? keep01 : recv01;   // j4..5 (from hi_p=1 producer)
      aw.w = hi ? keep23 : recv23;   // j6..7
      bf16x8 pf = __builtin_bit_cast(bf16x8, aw);
#pragma unroll
      for (int nt = 0; nt < 8; ++nt) {
        int pc = (s2 * 2 + hi) ^ (lo & 3);
        bf16x8 vf = ld_bf8(&Vt[(nt * 32 + lo) * 32 + pc * 8]);
        Oacc[nt] = __builtin_amdgcn_mfma_f32_32x32x16_bf16(pf, vf, Oacc[nt], 0, 0, 0);
      }
    }
    __syncthreads();
  }

  lsum += __shfl_xor(lsum, 32, 64);
  const int pidx = b * 4 + h;
  if (hi == 0)
    lpart[((size_t)(ks * 32 + pidx)) * 1024 + qt * 128 + w * 32 + lo] = lsum;

  // Opart[ks][p][e][q] bf16; q-groups of 4 consecutive -> 8B stores
#pragma unroll
  for (int nt = 0; nt < 8; ++nt) {
    size_t ebase = (((size_t)(ks * 32 + pidx)) * 256 + nt * 32 + lo) * 1024 +
                   qt * 128 + w * 32;
#pragma unroll
    for (int rb = 0; rb < 4; ++rb) {
      s16x4 pk;
#pragma unroll
      for (int r = 0; r < 4; ++r) pk[r] = (short)f2bf(Oacc[nt][rb * 4 + r]);
      *reinterpret_cast<s16x4*>(&Opart[ebase + rb * 8 + hi * 4]) = pk;
    }
  }
}

// ---------------------------------------------------------------------------
// combine: O = (Oa+Ob)/(la+lb), transpose [e][q] -> row-major [q][h*256+e]
// grid (16 qtiles of 64, H, B), 256 threads
// ---------------------------------------------------------------------------
__global__ void __launch_bounds__(256)
combine_kernel(const unsigned short* __restrict__ Opart,
               const float* __restrict__ lpart,
               unsigned short* __restrict__ Oall) {
  __shared__ float rl[64];
  __shared__ __align__(16) unsigned short T[64][264];
  const int t = threadIdx.x;
  const int qt = blockIdx.x, h = blockIdx.y, b = blockIdx.z;
  const int p = b * 4 + h;
  const int q0 = qt * 64;
  const size_t slabO = (size_t)32 * 256 * 1024;
  const size_t slabL = (size_t)32 * 1024;
  if (t < 64) {
    float la = lpart[(size_t)p * 1024 + q0 + t];
    float lb = lpart[slabL + (size_t)p * 1024 + q0 + t];
    rl[t] = 1.f / (la + lb);
  }
  __syncthreads();
  const int er = t >> 3, q8 = t & 7;   // e-row within 32, q-chunk
#pragma unroll
  for (int ei = 0; ei < 8; ++ei) {
    int e = ei * 32 + er;
    size_t idx = ((size_t)p * 256 + e) * 1024 + q0 + q8 * 8;
    u32x4 ua = *reinterpret_cast<const u32x4*>(&Opart[idx]);
    u32x4 ub = *reinterpret_cast<const u32x4*>(&Opart[slabO + idx]);
#pragma unroll
    for (int wd = 0; wd < 4; ++wd) {
      unsigned a = ((const unsigned*)&ua)[wd], bb2 = ((const unsigned*)&ub)[wd];
      float a0 = __builtin_bit_cast(float, a << 16);
      float a1 = __builtin_bit_cast(float, a & 0xFFFF0000u);
      float b0 = __builtin_bit_cast(float, bb2 << 16);
      float b1 = __builtin_bit_cast(float, bb2 & 0xFFFF0000u);
      int qA = q8 * 8 + wd * 2;
      T[qA + 0][e] = f2bf((a0 + b0) * rl[qA + 0]);
      T[qA + 1][e] = f2bf((a1 + b1) * rl[qA + 1]);
    }
  }
  __syncthreads();
  const int ql = t >> 2, ec = t & 3;
  const size_t orow = ((size_t)(b * 1024 + q0 + ql)) * 1024 + h * 256;
#pragma unroll
  for (int i = 0; i < 8; ++i) {
    int ch = ec * 8 + i;
    *reinterpret_cast<u32x4*>(&Oall[orow + ch * 8]) =
        *reinterpret_cast<const u32x4*>(&T[ql][ch * 8]);
  }
}

// ---------------------------------------------------------------------------
// residual + LayerNorm: one wave per row of 256
// ---------------------------------------------------------------------------
__global__ void __launch_bounds__(256)
fc_ln_kernel(const float* __restrict__ fc, const float* __restrict__ tgt,
             const float* __restrict__ g, const float* __restrict__ bb,
             float* __restrict__ y) {
  int row = blockIdx.x * 4 + (threadIdx.x >> 6);  // row = b*1024 + q
  int lane = threadIdx.x & 63;
  int b = row >> 10, q = row & 1023;
  const float* fr = fc + (size_t)row * 256;
  const float* tr = tgt + ((size_t)(q * 8 + b)) * 256;
  float x[4];
  float s = 0.f, ss = 0.f;
#pragma unroll
  for (int e = 0; e < 4; ++e) {
    x[e] = fr[lane + e * 64] + tr[lane + e * 64];
    s += x[e];
    ss += x[e] * x[e];
  }
#pragma unroll
  for (int d = 1; d < 64; d <<= 1) {
    s += __shfl_xor(s, d, 64);
    ss += __shfl_xor(ss, d, 64);
  }
  float mu = s * (1.f / 256.f);
  float var = ss * (1.f / 256.f) - mu * mu;
  float rs = rsqrtf(var + 1e-5f);
  float* yr = y + ((size_t)(q * 8 + b)) * 256;
#pragma unroll
  for (int e = 0; e < 4; ++e)
    yr[lane + e * 64] = (x[e] - mu) * rs * g[lane + e * 64] + bb[lane + e * 64];
}

// ---------------------------------------------------------------------------
extern "C" void kernel_launch(void* const* d_in, const int* in_sizes, int n_in,
                              void* d_out, int out_size, void* d_ws, size_t ws_size,
                              hipStream_t stream) {
  (void)in_sizes; (void)n_in; (void)out_size; (void)ws_size;
  const float* tgt    = (const float*)d_in[0];
  const float* memory = (const float*)d_in[1];
  const float* pos    = (const float*)d_in[2];
  const float* qpos   = (const float*)d_in[3];
  const float* Wq     = (const float*)d_in[4];
  const float* Wk     = (const float*)d_in[5];
  const float* Wv     = (const float*)d_in[6];
  const float* Wfc    = (const float*)d_in[7];
  const float* lng    = (const float*)d_in[8];
  const float* lnb    = (const float*)d_in[9];
  float* out = (float*)d_out;

  char* ws = (char*)d_ws;
  const size_t MB = 1024 * 1024;
  unsigned short* Wq_b  = (unsigned short*)(ws + 0);
  unsigned short* Wk_b  = (unsigned short*)(ws + 512 * 1024);
  unsigned short* Wv_b  = (unsigned short*)(ws + 1 * MB);
  unsigned short* Wfc_b = (unsigned short*)(ws + 1 * MB + 512 * 1024);
  unsigned short* A_q   = (unsigned short*)(ws + 2 * MB);    // [8192,256]   4MB
  unsigned short* A_k   = (unsigned short*)(ws + 6 * MB);    // [32768,256] 16MB
  unsigned short* A_v   = (unsigned short*)(ws + 22 * MB);   // [32768,256] 16MB
  unsigned short* Qall  = (unsigned short*)(ws + 38 * MB);   // [8192,1024] 16MB (pre-scaled 1/16)
  unsigned short* Kall  = (unsigned short*)(ws + 54 * MB);   // [32768,1024] 64MB
  unsigned short* VTb   = (unsigned short*)(ws + 118 * MB);  // [8192,4096] 64MB
  // after projections, A_q/A_k/A_v are dead -> attention partials alias them
  unsigned short* Opart = (unsigned short*)(ws + 2 * MB);    // 2x16.78MB = 33.55MB
  float* lpart          = (float*)(ws + 36 * MB);            // 256KB
  // after attention, VTb dead -> Oall + fcout alias it
  unsigned short* Oall  = (unsigned short*)(ws + 118 * MB);  // [8192,1024] 16.8MB
  float* fcout          = (float*)(ws + 140 * MB);           // [8192,256] fp32 8.4MB
  float* y = out;
  float* attn_mean = out + (size_t)LQ * NBATCH * DM;

  int n_q = LQ * NBATCH * DM;   // 2,097,152
  int n_k = LK * NBATCH * DM;   // 8,388,608
  prep_add_kernel<<<(n_q / 8 + 255) / 256, 256, 0, stream>>>(tgt, qpos, A_q, LQ, n_q / 8);
  prep_add_kernel<<<(n_k / 8 + 255) / 256, 256, 0, stream>>>(memory, pos, A_k, LK, n_k / 8);
  prep_add_kernel<<<(n_k / 8 + 255) / 256, 256, 0, stream>>>(memory, nullptr, A_v, LK, n_k / 8);
  int n_w8 = 1024 * 256 / 8;
  conv_bf16_kernel<<<(n_w8 + 255) / 256, 256, 0, stream>>>(Wq, Wq_b, n_w8);
  conv_bf16_kernel<<<(n_w8 + 255) / 256, 256, 0, stream>>>(Wk, Wk_b, n_w8);
  conv_bf16_kernel<<<(n_w8 + 255) / 256, 256, 0, stream>>>(Wv, Wv_b, n_w8);
  conv_bf16_kernel<<<(n_w8 + 255) / 256, 256, 0, stream>>>(Wfc, Wfc_b, n_w8);

  // Q projection (1/16 folded), bf16 out
  gemm_nt_kernel<1><<<dim3(8, 64, 1), 256, 0, stream>>>(
      A_q, 256, 0LL, Wq_b, 256, 0LL, (void*)Qall, 1024, 0LL, 256, 0.0625f);
  // K projection
  gemm_nt_kernel<1><<<dim3(8, 256, 1), 256, 0, stream>>>(
      A_k, 256, 0LL, Wk_b, 256, 0LL, (void*)Kall, 1024, 0LL, 256, 1.0f);
  // V projection, transposed out: VT[(b*1024+e)*4096 + k]
  gemm_nt_kernel<2><<<dim3(8, 256, 1), 256, 0, stream>>>(
      A_v, 256, 0LL, Wv_b, 256, 0LL, (void*)VTb, 0, 0LL, 256, 1.0f);
  // attn_mean = 0.25 * Qall_b . Kall_b^T  (concat-dot == sum over heads)
  gemm_nt_kernel<0><<<dim3(32, 8, 8), 256, 0, stream>>>(
      Qall, 1024, (long long)(1024 * 1024), Kall, 1024, (long long)(4096 * 1024),
      (void*)attn_mean, 4096, (long long)4096 * 1024, 1024, 0.25f);
  // flash attention (k-split 2) -> partials
  attn_kernel<<<dim3(16, NH, NBATCH), 256, 0, stream>>>(Qall, Kall, VTb, Opart, lpart);
  // combine partials -> Oall row-major [8192,1024]
  combine_kernel<<<dim3(16, NH, NBATCH), 256, 0, stream>>>(Opart, lpart, Oall);
  // fc: [8192,1024] @ Wfc[256,1024]^T -> fp32
  gemm_nt_kernel<0><<<dim3(2, 64, 1), 256, 0, stream>>>(
      Oall, 1024, 0LL, Wfc_b, 1024, 0LL, (void*)fcout, 256, 0LL, 1024, 1.0f);
  // residual + LN
  fc_ln_kernel<<<2048, 256, 0, stream>>>(fcout, tgt, lng, lnb, y);
}

// Round 3
// 631.197 us; speedup vs baseline: 1.4814x; 1.4814x over previous
//
#include <hip/hip_runtime.h>
#include <cstdint>
#include <cstddef>

#define LQ 1024
#define LK 4096
#define NBATCH 8
#define DM 256
#define NH 4

typedef __attribute__((ext_vector_type(8))) __bf16 bf16x8;
typedef __attribute__((ext_vector_type(4))) float f32x4;
typedef __attribute__((ext_vector_type(4))) unsigned int u32x4;
typedef __attribute__((ext_vector_type(4))) short s16x4;

__device__ __forceinline__ unsigned short f2bf(float f) {
  unsigned int u = __builtin_bit_cast(unsigned int, f);
  u += 0x7FFFu + ((u >> 16) & 1u);  // RNE
  return (unsigned short)(u >> 16);
}
__device__ __forceinline__ unsigned pack2(float a, float b) {
  return (unsigned)f2bf(a) | ((unsigned)f2bf(b) << 16);
}
__device__ __forceinline__ bf16x8 ld_bf8(const unsigned short* p) {
  u32x4 u = *reinterpret_cast<const u32x4*>(p);
  return __builtin_bit_cast(bf16x8, u);
}
__device__ __forceinline__ f32x4 zero4() {
  f32x4 v; v.x = 0.f; v.y = 0.f; v.z = 0.f; v.w = 0.f; return v;
}

// async global->LDS, 16B per lane; LDS dest = wave-uniform base + lane*16
#define ASYNC16(ldsp, gp)                                                      \
  __builtin_amdgcn_global_load_lds(                                            \
      (const __attribute__((address_space(1))) unsigned int*)(gp),             \
      (__attribute__((address_space(3))) unsigned int*)(ldsp), 16, 0, 0)

// ---------------------------------------------------------------------------
// prep (x8 vectorized): out[(b*L+l)*256+d] = bf16(a[(l*8+b)*256+d] (+badd))
// ---------------------------------------------------------------------------
__global__ void prep_add_kernel(const float* __restrict__ a,
                                const float* __restrict__ badd,
                                unsigned short* __restrict__ out,
                                int L, int n8) {
  int i = blockIdx.x * blockDim.x + threadIdx.x;
  if (i >= n8) return;
  int base = i * 8;
  int d = base & 255;
  int rest = base >> 8;
  int bb = rest & 7, l = rest >> 3;
  f32x4 x0 = *reinterpret_cast<const f32x4*>(a + base);
  f32x4 x1 = *reinterpret_cast<const f32x4*>(a + base + 4);
  if (badd) {
    f32x4 y0 = *reinterpret_cast<const f32x4*>(badd + base);
    f32x4 y1 = *reinterpret_cast<const f32x4*>(badd + base + 4);
    x0 += y0; x1 += y1;
  }
  u32x4 o;
  o.x = pack2(x0.x, x0.y); o.y = pack2(x0.z, x0.w);
  o.z = pack2(x1.x, x1.y); o.w = pack2(x1.z, x1.w);
  *reinterpret_cast<u32x4*>(out + (((size_t)bb * L + l) << 8) + d) = o;
}

__global__ void conv_bf16_kernel(const float* __restrict__ src,
                                 unsigned short* __restrict__ dst, int n8) {
  int i = blockIdx.x * blockDim.x + threadIdx.x;
  if (i >= n8) return;
  int base = i * 8;
  f32x4 x0 = *reinterpret_cast<const f32x4*>(src + base);
  f32x4 x1 = *reinterpret_cast<const f32x4*>(src + base + 4);
  u32x4 o;
  o.x = pack2(x0.x, x0.y); o.y = pack2(x0.z, x0.w);
  o.z = pack2(x1.x, x1.y); o.w = pack2(x1.z, x1.w);
  *reinterpret_cast<u32x4*>(dst + base) = o;
}

// ---------------------------------------------------------------------------
// NT GEMM (unchanged from round 2): global_load_lds(16B), XOR-swizzled LDS.
// ---------------------------------------------------------------------------
template <int OUT_MODE>
__global__ void __launch_bounds__(256)
gemm_nt_kernel(const unsigned short* __restrict__ A, int lda, long long sA,
               const unsigned short* __restrict__ B, int ldb, long long sB,
               void* __restrict__ Cv, int ldc, long long sC,
               int K, float alpha) {
  __shared__ __align__(16) unsigned short As[128 * 64];
  __shared__ __align__(16) unsigned short Bs[128 * 64];
  const int t = threadIdx.x;
  const int bm0 = blockIdx.y * 128;
  const int bn0 = blockIdx.x * 128;
  A += (size_t)blockIdx.z * sA + (size_t)bm0 * lda;
  B += (size_t)blockIdx.z * sB + (size_t)bn0 * ldb;
  const int lane = t & 63, w = t >> 6;
  const int wm = (w >> 1) * 64, wn = (w & 1) * 64;
  const int lr = lane & 15, quad = lane >> 4;
  const int srl = lane >> 3;
  const int sc = (lane & 7) ^ (srl & 7);

  f32x4 acc[4][4];
#pragma unroll
  for (int i = 0; i < 4; ++i)
#pragma unroll
    for (int j = 0; j < 4; ++j) acc[i][j] = zero4();

  for (int k0 = 0; k0 < K; k0 += 64) {
#pragma unroll
    for (int i = 0; i < 4; ++i) {
      int r0 = w * 32 + i * 8;
      ASYNC16(&As[r0 * 64], &A[(size_t)(r0 + srl) * lda + k0 + sc * 8]);
      ASYNC16(&Bs[r0 * 64], &B[(size_t)(r0 + srl) * ldb + k0 + sc * 8]);
    }
    __syncthreads();
#pragma unroll
    for (int ks = 0; ks < 2; ++ks) {
      bf16x8 af[4], bfv[4];
#pragma unroll
      for (int i = 0; i < 4; ++i) {
        int m = wm + i * 16 + lr;
        int pc = (ks * 4 + quad) ^ (lr & 7);
        af[i] = ld_bf8(&As[m * 64 + pc * 8]);
      }
#pragma unroll
      for (int j = 0; j < 4; ++j) {
        int n = wn + j * 16 + lr;
        int pc = (ks * 4 + quad) ^ (lr & 7);
        bfv[j] = ld_bf8(&Bs[n * 64 + pc * 8]);
      }
#pragma unroll
      for (int i = 0; i < 4; ++i)
#pragma unroll
        for (int j = 0; j < 4; ++j)
          acc[i][j] = __builtin_amdgcn_mfma_f32_16x16x32_bf16(af[i], bfv[j], acc[i][j], 0, 0, 0);
    }
    __syncthreads();
  }

  if (OUT_MODE == 0) {
    float* C = (float*)Cv + (size_t)blockIdx.z * sC;
#pragma unroll
    for (int i = 0; i < 4; ++i) {
      int m0 = bm0 + wm + i * 16 + quad * 4;
#pragma unroll
      for (int j = 0; j < 4; ++j) {
        int n = bn0 + wn + j * 16 + lr;
#pragma unroll
        for (int r = 0; r < 4; ++r)
          C[(size_t)(m0 + r) * ldc + n] = acc[i][j][r] * alpha;
      }
    }
  } else if (OUT_MODE == 1) {
    unsigned short* C = (unsigned short*)Cv + (size_t)blockIdx.z * sC;
#pragma unroll
    for (int i = 0; i < 4; ++i) {
      int m0 = bm0 + wm + i * 16 + quad * 4;
#pragma unroll
      for (int j = 0; j < 4; ++j) {
        int n = bn0 + wn + j * 16 + lr;
#pragma unroll
        for (int r = 0; r < 4; ++r)
          C[(size_t)(m0 + r) * ldc + n] = f2bf(acc[i][j][r] * alpha);
      }
    }
  } else {
    unsigned short* C = (unsigned short*)Cv;
#pragma unroll
    for (int i = 0; i < 4; ++i) {
      int m0 = bm0 + wm + i * 16 + quad * 4;
      int bb = m0 >> 12;
      int kp = m0 & 4095;
#pragma unroll
      for (int j = 0; j < 4; ++j) {
        int n = bn0 + wn + j * 16 + lr;
        s16x4 pk;
#pragma unroll
        for (int r = 0; r < 4; ++r) pk[r] = (short)f2bf(acc[i][j][r] * alpha);
        *reinterpret_cast<s16x4*>(&C[((size_t)(bb * 1024 + n)) * 4096 + kp]) = pk;
      }
    }
  }
}

// ---------------------------------------------------------------------------
// Flash attention v3: 16x16x32 MFMA, double-buffered async staging, single
// barrier per k-tile (prefetch t+1 issued before compute of t).
// grid (16=qt*2+ks, H, B), 256 thr = 4 waves; wave owns 32 q rows.
// QK: S[2mt][2nt] tiles (ILP 4); P C->A layout via ds_bpermute.
// No-max softmax (logits ~ +-0.6). Outputs match round-2 combine format.
// ---------------------------------------------------------------------------
__global__ void __launch_bounds__(256, 2)
attn_kernel(const unsigned short* __restrict__ Qg,
            const unsigned short* __restrict__ Kg,
            const unsigned short* __restrict__ VTg,
            unsigned short* __restrict__ Opart,
            float* __restrict__ lpart) {
  __shared__ __align__(16) unsigned short Kt[2][32 * 256];  // [kpos][d], chunk^ (row&7)
  __shared__ __align__(16) unsigned short Vt[2][256 * 32];  // [e][kpos], chunk^ (row&3)
  const int t = threadIdx.x;
  const int qt = blockIdx.x >> 1, ks = blockIdx.x & 1;
  const int h = blockIdx.y, b = blockIdx.z;
  const int lane = t & 63, w = t >> 6;
  const int lr = lane & 15, quad = lane >> 4;

  // Q B-frags: qf[nt][s]: q = qt*128+w*32+nt*16+lr, d = s*32 + quad*8..+7
  const unsigned short* Qrow0 =
      Qg + ((size_t)(b * 1024 + qt * 128 + w * 32 + lr)) * 1024 + h * 256;
  bf16x8 qf[2][8];
#pragma unroll
  for (int s = 0; s < 8; ++s) {
    qf[0][s] = ld_bf8(&Qrow0[s * 32 + quad * 8]);
    qf[1][s] = ld_bf8(&Qrow0[16 * 1024 + s * 32 + quad * 8]);
  }

  f32x4 Oacc[16][2];
#pragma unroll
  for (int m2 = 0; m2 < 16; ++m2) {
    Oacc[m2][0] = zero4();
    Oacc[m2][1] = zero4();
  }
  float lsum_r[2] = {0.f, 0.f};

  const unsigned short* Kb =
      Kg + ((size_t)(b * 4096 + ks * 2048)) * 1024 + h * 256;
  const unsigned short* Vb =
      VTg + ((size_t)(b * 1024 + h * 256)) * 4096 + ks * 2048;

  // staging index precompute
  const int k_rsub = lane >> 5;                 // row within pair
  const int k_chunk = lane & 31;                // phys chunk (of 32)
  const int v_rsub = lane >> 2;                 // row within 16
  const int v_chunk = lane & 3;                 // phys chunk (of 4)

#define ISSUE_TILE(kt, bufsel)                                                 \
  {                                                                            \
    _Pragma("unroll") for (int i = 0; i < 4; ++i) {                            \
      int r0 = w * 8 + i * 2;                                                  \
      int krow = r0 + k_rsub;                                                  \
      int kc = k_chunk ^ (krow & 7);                                           \
      ASYNC16(&Kt[bufsel][r0 * 256], &Kb[(size_t)((kt) + krow) * 1024 + kc * 8]); \
      int vr0 = (w * 4 + i) * 16;                                              \
      int ve = vr0 + v_rsub;                                                   \
      int vc = v_chunk ^ (ve & 3);                                             \
      ASYNC16(&Vt[bufsel][vr0 * 32], &Vb[(size_t)ve * 4096 + (kt) + vc * 8]);  \
    }                                                                          \
  }

  ISSUE_TILE(0, 0)
  __syncthreads();

  const int bpermA = (((quad & 1) * 32) + lr) * 4;  // src lane qs0*16+lr, bytes
  const int bpermB = bpermA + 64;                   // qs0+1

  for (int kt = 0; kt < 2048; kt += 32) {
    const int pbuf = (kt >> 5) & 1;
    // prefetch next tile into the other buffer (tail prefetch reads junk into
    // a never-read buffer; addresses stay inside the workspace)
    ISSUE_TILE(kt + 32, pbuf ^ 1)

    const unsigned short* Ktp = Kt[pbuf];
    const unsigned short* Vtp = Vt[pbuf];

    // S^T[kpos][q]: A = K (m=kpos), B = Q regs. 2 m-tiles x 2 n-tiles, ILP 4.
    f32x4 S[2][2];
    S[0][0] = zero4(); S[0][1] = zero4();
    S[1][0] = zero4(); S[1][1] = zero4();
#pragma unroll
    for (int s = 0; s < 8; ++s) {
      int pc = ((s * 4 + quad) ^ (lr & 7)) * 8;
      bf16x8 kf0 = ld_bf8(&Ktp[lr * 256 + pc]);
      bf16x8 kf1 = ld_bf8(&Ktp[(16 + lr) * 256 + pc]);
      S[0][0] = __builtin_amdgcn_mfma_f32_16x16x32_bf16(kf0, qf[0][s], S[0][0], 0, 0, 0);
      S[0][1] = __builtin_amdgcn_mfma_f32_16x16x32_bf16(kf0, qf[1][s], S[0][1], 0, 0, 0);
      S[1][0] = __builtin_amdgcn_mfma_f32_16x16x32_bf16(kf1, qf[0][s], S[1][0], 0, 0, 0);
      S[1][1] = __builtin_amdgcn_mfma_f32_16x16x32_bf16(kf1, qf[1][s], S[1][1], 0, 0, 0);
    }

    // exp + pack to bf16 pairs
    unsigned pk[2][2][2];
#pragma unroll
    for (int mt = 0; mt < 2; ++mt)
#pragma unroll
      for (int nt = 0; nt < 2; ++nt) {
        float p0 = __expf(S[mt][nt][0]);
        float p1 = __expf(S[mt][nt][1]);
        float p2 = __expf(S[mt][nt][2]);
        float p3 = __expf(S[mt][nt][3]);
        lsum_r[nt] += (p0 + p1) + (p2 + p3);
        pk[mt][nt][0] = pack2(p0, p1);
        pk[mt][nt][1] = pack2(p2, p3);
      }

    // P^T C-layout -> B-operand A..: dest lane (lr,quad) elem j needs
    // kpos=quad*8+j, q=nt*16+lr  => src tile mt=quad>>1, src quad
    // (quad&1)*2+(j>>2), reg j&3.  ds_bpermute both tiles + select.
    bf16x8 pfrag[2];
#pragma unroll
    for (int nt = 0; nt < 2; ++nt) {
      u32x4 bfw;
#pragma unroll
      for (int w2 = 0; w2 < 2; ++w2) {
        int f0 = __builtin_amdgcn_ds_bpermute(bpermA, (int)pk[0][nt][w2]);
        int f1 = __builtin_amdgcn_ds_bpermute(bpermA, (int)pk[1][nt][w2]);
        bfw[w2] = (unsigned)(quad < 2 ? f0 : f1);
        int g0 = __builtin_amdgcn_ds_bpermute(bpermB, (int)pk[0][nt][w2]);
        int g1 = __builtin_amdgcn_ds_bpermute(bpermB, (int)pk[1][nt][w2]);
        bfw[2 + w2] = (unsigned)(quad < 2 ? g0 : g1);
      }
      pfrag[nt] = __builtin_bit_cast(bf16x8, bfw);
    }

    // PV: O^T[e][q] += V^T * P^T ; A = V^T (m=e), k = 32 kpos, 1 k-step
#pragma unroll
    for (int m2 = 0; m2 < 16; ++m2) {
      bf16x8 vf = ld_bf8(&Vtp[(m2 * 16 + lr) * 32 + (quad ^ (lr & 3)) * 8]);
      Oacc[m2][0] = __builtin_amdgcn_mfma_f32_16x16x32_bf16(vf, pfrag[0], Oacc[m2][0], 0, 0, 0);
      Oacc[m2][1] = __builtin_amdgcn_mfma_f32_16x16x32_bf16(vf, pfrag[1], Oacc[m2][1], 0, 0, 0);
    }
    __syncthreads();
  }
#undef ISSUE_TILE

  const int pidx = b * 4 + h;
  // lsum: reduce across quads (q lives in lr; partials spread over quad)
#pragma unroll
  for (int nt = 0; nt < 2; ++nt) {
    float l = lsum_r[nt];
    l += __shfl_xor(l, 16, 64);
    l += __shfl_xor(l, 32, 64);
    if (quad == 0)
      lpart[((size_t)(ks * 32 + pidx)) * 1024 + qt * 128 + w * 32 + nt * 16 + lr] = l;
  }

  // Opart[ks][p][e][q] bf16 (same format as round-2 combine expects)
  const size_t base = ((size_t)(ks * 32 + pidx)) * 256 * 1024;
  const int qg0 = qt * 128 + w * 32 + lr;
#pragma unroll
  for (int m2 = 0; m2 < 16; ++m2) {
#pragma unroll
    for (int nt = 0; nt < 2; ++nt) {
#pragma unroll
      for (int r = 0; r < 4; ++r) {
        int e = m2 * 16 + quad * 4 + r;
        Opart[base + (size_t)e * 1024 + qg0 + nt * 16] = f2bf(Oacc[m2][nt][r]);
      }
    }
  }
}

// ---------------------------------------------------------------------------
// combine: O = (Oa+Ob)/(la+lb), transpose [e][q] -> row-major [q][h*256+e]
// ---------------------------------------------------------------------------
__global__ void __launch_bounds__(256)
combine_kernel(const unsigned short* __restrict__ Opart,
               const float* __restrict__ lpart,
               unsigned short* __restrict__ Oall) {
  __shared__ float rl[64];
  __shared__ __align__(16) unsigned short T[64][264];
  const int t = threadIdx.x;
  const int qt = blockIdx.x, h = blockIdx.y, b = blockIdx.z;
  const int p = b * 4 + h;
  const int q0 = qt * 64;
  const size_t slabO = (size_t)32 * 256 * 1024;
  const size_t slabL = (size_t)32 * 1024;
  if (t < 64) {
    float la = lpart[(size_t)p * 1024 + q0 + t];
    float lb = lpart[slabL + (size_t)p * 1024 + q0 + t];
    rl[t] = 1.f / (la + lb);
  }
  __syncthreads();
  const int er = t >> 3, q8 = t & 7;
#pragma unroll
  for (int ei = 0; ei < 8; ++ei) {
    int e = ei * 32 + er;
    size_t idx = ((size_t)p * 256 + e) * 1024 + q0 + q8 * 8;
    u32x4 ua = *reinterpret_cast<const u32x4*>(&Opart[idx]);
    u32x4 ub = *reinterpret_cast<const u32x4*>(&Opart[slabO + idx]);
#pragma unroll
    for (int wd = 0; wd < 4; ++wd) {
      unsigned a = ((const unsigned*)&ua)[wd], bb2 = ((const unsigned*)&ub)[wd];
      float a0 = __builtin_bit_cast(float, a << 16);
      float a1 = __builtin_bit_cast(float, a & 0xFFFF0000u);
      float b0 = __builtin_bit_cast(float, bb2 << 16);
      float b1 = __builtin_bit_cast(float, bb2 & 0xFFFF0000u);
      int qA = q8 * 8 + wd * 2;
      T[qA + 0][e] = f2bf((a0 + b0) * rl[qA + 0]);
      T[qA + 1][e] = f2bf((a1 + b1) * rl[qA + 1]);
    }
  }
  __syncthreads();
  const int ql = t >> 2, ec = t & 3;
  const size_t orow = ((size_t)(b * 1024 + q0 + ql)) * 1024 + h * 256;
#pragma unroll
  for (int i = 0; i < 8; ++i) {
    int ch = ec * 8 + i;
    *reinterpret_cast<u32x4*>(&Oall[orow + ch * 8]) =
        *reinterpret_cast<const u32x4*>(&T[ql][ch * 8]);
  }
}

// ---------------------------------------------------------------------------
// residual + LayerNorm: one wave per row of 256
// ---------------------------------------------------------------------------
__global__ void __launch_bounds__(256)
fc_ln_kernel(const float* __restrict__ fc, const float* __restrict__ tgt,
             const float* __restrict__ g, const float* __restrict__ bb,
             float* __restrict__ y) {
  int row = blockIdx.x * 4 + (threadIdx.x >> 6);
  int lane = threadIdx.x & 63;
  int b = row >> 10, q = row & 1023;
  const float* fr = fc + (size_t)row * 256;
  const float* tr = tgt + ((size_t)(q * 8 + b)) * 256;
  float x[4];
  float s = 0.f, ss = 0.f;
#pragma unroll
  for (int e = 0; e < 4; ++e) {
    x[e] = fr[lane + e * 64] + tr[lane + e * 64];
    s += x[e];
    ss += x[e] * x[e];
  }
#pragma unroll
  for (int d = 1; d < 64; d <<= 1) {
    s += __shfl_xor(s, d, 64);
    ss += __shfl_xor(ss, d, 64);
  }
  float mu = s * (1.f / 256.f);
  float var = ss * (1.f / 256.f) - mu * mu;
  float rs = rsqrtf(var + 1e-5f);
  float* yr = y + ((size_t)(q * 8 + b)) * 256;
#pragma unroll
  for (int e = 0; e < 4; ++e)
    yr[lane + e * 64] = (x[e] - mu) * rs * g[lane + e * 64] + bb[lane + e * 64];
}

// ---------------------------------------------------------------------------
extern "C" void kernel_launch(void* const* d_in, const int* in_sizes, int n_in,
                              void* d_out, int out_size, void* d_ws, size_t ws_size,
                              hipStream_t stream) {
  (void)in_sizes; (void)n_in; (void)out_size; (void)ws_size;
  const float* tgt    = (const float*)d_in[0];
  const float* memory = (const float*)d_in[1];
  const float* pos    = (const float*)d_in[2];
  const float* qpos   = (const float*)d_in[3];
  const float* Wq     = (const float*)d_in[4];
  const float* Wk     = (const float*)d_in[5];
  const float* Wv     = (const float*)d_in[6];
  const float* Wfc    = (const float*)d_in[7];
  const float* lng    = (const float*)d_in[8];
  const float* lnb    = (const float*)d_in[9];
  float* out = (float*)d_out;

  char* ws = (char*)d_ws;
  const size_t MB = 1024 * 1024;
  unsigned short* Wq_b  = (unsigned short*)(ws + 0);
  unsigned short* Wk_b  = (unsigned short*)(ws + 512 * 1024);
  unsigned short* Wv_b  = (unsigned short*)(ws + 1 * MB);
  unsigned short* Wfc_b = (unsigned short*)(ws + 1 * MB + 512 * 1024);
  unsigned short* A_q   = (unsigned short*)(ws + 2 * MB);
  unsigned short* A_k   = (unsigned short*)(ws + 6 * MB);
  unsigned short* A_v   = (unsigned short*)(ws + 22 * MB);
  unsigned short* Qall  = (unsigned short*)(ws + 38 * MB);
  unsigned short* Kall  = (unsigned short*)(ws + 54 * MB);
  unsigned short* VTb   = (unsigned short*)(ws + 118 * MB);
  unsigned short* Opart = (unsigned short*)(ws + 2 * MB);
  float* lpart          = (float*)(ws + 36 * MB);
  unsigned short* Oall  = (unsigned short*)(ws + 118 * MB);
  float* fcout          = (float*)(ws + 140 * MB);
  float* y = out;
  float* attn_mean = out + (size_t)LQ * NBATCH * DM;

  int n_q = LQ * NBATCH * DM;
  int n_k = LK * NBATCH * DM;
  prep_add_kernel<<<(n_q / 8 + 255) / 256, 256, 0, stream>>>(tgt, qpos, A_q, LQ, n_q / 8);
  prep_add_kernel<<<(n_k / 8 + 255) / 256, 256, 0, stream>>>(memory, pos, A_k, LK, n_k / 8);
  prep_add_kernel<<<(n_k / 8 + 255) / 256, 256, 0, stream>>>(memory, nullptr, A_v, LK, n_k / 8);
  int n_w8 = 1024 * 256 / 8;
  conv_bf16_kernel<<<(n_w8 + 255) / 256, 256, 0, stream>>>(Wq, Wq_b, n_w8);
  conv_bf16_kernel<<<(n_w8 + 255) / 256, 256, 0, stream>>>(Wk, Wk_b, n_w8);
  conv_bf16_kernel<<<(n_w8 + 255) / 256, 256, 0, stream>>>(Wv, Wv_b, n_w8);
  conv_bf16_kernel<<<(n_w8 + 255) / 256, 256, 0, stream>>>(Wfc, Wfc_b, n_w8);

  gemm_nt_kernel<1><<<dim3(8, 64, 1), 256, 0, stream>>>(
      A_q, 256, 0LL, Wq_b, 256, 0LL, (void*)Qall, 1024, 0LL, 256, 0.0625f);
  gemm_nt_kernel<1><<<dim3(8, 256, 1), 256, 0, stream>>>(
      A_k, 256, 0LL, Wk_b, 256, 0LL, (void*)Kall, 1024, 0LL, 256, 1.0f);
  gemm_nt_kernel<2><<<dim3(8, 256, 1), 256, 0, stream>>>(
      A_v, 256, 0LL, Wv_b, 256, 0LL, (void*)VTb, 0, 0LL, 256, 1.0f);
  gemm_nt_kernel<0><<<dim3(32, 8, 8), 256, 0, stream>>>(
      Qall, 1024, (long long)(1024 * 1024), Kall, 1024, (long long)(4096 * 1024),
      (void*)attn_mean, 4096, (long long)4096 * 1024, 1024, 0.25f);
  attn_kernel<<<dim3(16, NH, NBATCH), 256, 0, stream>>>(Qall, Kall, VTb, Opart, lpart);
  combine_kernel<<<dim3(16, NH, NBATCH), 256, 0, stream>>>(Opart, lpart, Oall);
  gemm_nt_kernel<0><<<dim3(2, 64, 1), 256, 0, stream>>>(
      Oall, 1024, 0LL, Wfc_b, 1024, 0LL, (void*)fcout, 256, 0LL, 1024, 1.0f);
  fc_ln_kernel<<<2048, 256, 0, stream>>>(fcout, tgt, lng, lnb, y);
}